// Round 11
// baseline (374.272 us; speedup 1.0000x reference)
//
#include <hip/hip_runtime.h>

#define N 20000
#define E 200000
#define IN 128
#define OUT 128
#define NB 8
#define SI 16
#define SO 16
#define R 230
#define T 365
#define CAP 64                       // fixed msg slots per destination node

#define NSH 8                        // relation cursor shards
#define NSEG (R * NSH)               // 1840 (r,shard) segments

#define MSG_TILES (E / 32)           // 6250
#define SL_BLOCKS 625                // self-loop role: 32 nodes/block
#define TE_BLOCKS 313                // time-embed role: 64 nodes/block
#define AUX_BLOCKS (SL_BLOCKS + TE_BLOCKS)   // 938
#define GRID3 (AUX_BLOCKS * 8)               // 7504 (aux = every 8th block)

// Scratch in module .bss (zero-initialized at load). d_ws untouched;
// kernel_launch does plain kernel launches only (graph-capture safe).
// Cross-launch invariant: node_kernel's tail re-zeroes g_cur_d / g_cnt_r /
// g_done for the NEXT launch; first launch rides .bss zero-init. g_cur_r is
// rebuilt from g_cnt_r by K1's tail every launch.
__device__ float  g_W_t[(size_t)R * NB * SO * SI]; // W transposed: [r][b][ol][i]
__device__ ushort g_msg[(size_t)N * CAP * OUT];    // bf16 messages, slotted
__device__ float  g_sl[(size_t)N * OUT];           // self-loop GEMM + bias
__device__ int    g_cur_d[N];                      // slot cursors / in-degree
__device__ int    g_cnt_r[NSEG * 16];              // line-padded shard counts
__device__ int    g_cur_r[NSEG * 16];              // shard cursors
__device__ int    g_eid_r[E];                      // edge ids, (r,shard)-sorted
__device__ unsigned g_done;

__device__ __forceinline__ ushort f2bf(float f) {  // RNE float->bf16
    unsigned u = __float_as_uint(f);
    return (ushort)((u + 0x7fffu + ((u >> 16) & 1u)) >> 16);
}
__device__ __forceinline__ float bflo(unsigned m) { return __uint_as_float(m << 16); }
__device__ __forceinline__ float bfhi(unsigned m) { return __uint_as_float(m & 0xffff0000u); }
__device__ __forceinline__ int ld_agent(const int* p) {
    return __hip_atomic_load(p, __ATOMIC_RELAXED, __HIP_MEMORY_SCOPE_AGENT);
}

// K1: W transpose + sharded relation histogram; LAST finishing block runs the
// REL-ONLY offset scan (1840 counters, 8 independent loads/thread + LDS scan
// — tiny, unlike R7/R8's fatal 20K dst-scan tails).
__global__ __launch_bounds__(256) void build_kernel(
        const float* __restrict__ weight,
        const int* __restrict__ edge_type) {
    __shared__ int lh[NSEG];
    __shared__ int sscan[256];
    __shared__ int s_last;
    const int tid  = threadIdx.x;
    const int gtid = blockIdx.x * 256 + tid;
    const int GSZ  = gridDim.x * 256;

    for (int t = gtid; t < R * NB * SI * SO; t += GSZ) {
        int r  = t >> 11;
        int b  = (t >> 8) & 7;
        int ol = (t >> 4) & 15;
        int i  = t & 15;
        g_W_t[t] = weight[(size_t)r * 2048 + b * 256 + i * 16 + ol];
    }
    for (int j = tid; j < NSEG; j += 256) lh[j] = 0;
    __syncthreads();
    for (int e = gtid; e < E; e += GSZ)
        atomicAdd(&lh[edge_type[e] * NSH + (e & (NSH - 1))], 1);
    __syncthreads();
    for (int j = tid; j < NSEG; j += 256)
        if (lh[j]) atomicAdd(&g_cnt_r[j * 16], lh[j]);

    // ---- completion detection ----
    __syncthreads();
    if (tid == 0) {
        __threadfence();
        unsigned d = atomicAdd(&g_done, 1u);
        s_last = (d == (unsigned)(gridDim.x - 1)) ? 1 : 0;
    }
    __syncthreads();
    if (!s_last) return;
    __threadfence();

    // ---- rel-only alloc: 8 counts/thread -> LDS scan -> write cursors ----
    int c[8];
    const int j0 = tid * 8;
#pragma unroll
    for (int u = 0; u < 8; ++u) {
        int j = j0 + u;
        c[u] = (j < NSEG) ? ld_agent(&g_cnt_r[j * 16]) : 0;
    }
    int s = 0;
#pragma unroll
    for (int u = 0; u < 8; ++u) s += c[u];
    sscan[tid] = s;
    __syncthreads();
    for (int d = 1; d < 256; d <<= 1) {
        int v = (tid >= d) ? sscan[tid - d] : 0;
        __syncthreads();
        sscan[tid] += v;
        __syncthreads();
    }
    int run = (tid > 0) ? sscan[tid - 1] : 0;
#pragma unroll
    for (int u = 0; u < 8; ++u) {
        int j = j0 + u;
        if (j < NSEG) g_cur_r[j * 16] = run;
        run += c[u];
    }
}

// K2: relation scatter (sharded cursors; dst handling lives in K3's meta).
__global__ void scatter_kernel(const int* __restrict__ edge_type) {
    int e = blockIdx.x * blockDim.x + threadIdx.x;
    if (e < E) {
        int seg = edge_type[e] * NSH + (e & (NSH - 1));
        int pr = atomicAdd(&g_cur_r[seg * 16], 1);
        g_eid_r[pr] = e;
    }
}

// K3: three block roles (aux = every 8th block):
//  - msg role: rel-sorted 32-edge tiles, W[r] in 16 registers (fast path
//    ~96%), cooperative h-row LDS gather, dst slot claimed by one atomic in
//    the meta phase, bf16 NT store at msg[dst*CAP+slot].
//  - sl role: self-loop GEMM + bias -> g_sl (hidden under msg's shadow).
//  - te role: time-embedding gather -> out2 directly.
__global__ __launch_bounds__(256) void fused_kernel(
        const float* __restrict__ h,
        const float* __restrict__ edge_norm,
        const int* __restrict__ edge_src,
        const int* __restrict__ edge_dst,
        const int* __restrict__ edge_type,
        const float* __restrict__ loop_weight,
        const float* __restrict__ h_bias,
        const float* __restrict__ time_embed,
        const int* __restrict__ time_idx,
        float* __restrict__ out) {
    __shared__ __attribute__((aligned(16))) float hsm[32 * 132];
    __shared__ int   ssrc[32], stype[32], spos[32];
    __shared__ float snorm[32];

    const int bid = blockIdx.x;
    const int tid = threadIdx.x;

    if ((bid & 7) == 7) {
        const int a = bid >> 3;
        if (a < SL_BLOCKS) {
            // ---- self-loop role: nodes a*32 .. a*32+31 ----
            const int q    = tid & 63;
            const int wave = tid >> 6;
            const int nb   = a * 32 + wave * 8;
            const float2* lw2 = reinterpret_cast<const float2*>(loop_weight);
            float sL[8], sH[8];
#pragma unroll
            for (int j = 0; j < 8; ++j) { sL[j] = 0.f; sH[j] = 0.f; }
            for (int i0 = 0; i0 < IN; i0 += 4) {
                float2 w0 = lw2[(size_t)(i0 + 0) * 64 + q];
                float2 w1 = lw2[(size_t)(i0 + 1) * 64 + q];
                float2 w2 = lw2[(size_t)(i0 + 2) * 64 + q];
                float2 w3 = lw2[(size_t)(i0 + 3) * 64 + q];
#pragma unroll
                for (int j = 0; j < 8; ++j) {
                    float4 v = *reinterpret_cast<const float4*>(
                        h + (size_t)(nb + j) * IN + i0);   // wave-broadcast
                    sL[j] = fmaf(v.x, w0.x, sL[j]); sL[j] = fmaf(v.y, w1.x, sL[j]);
                    sL[j] = fmaf(v.z, w2.x, sL[j]); sL[j] = fmaf(v.w, w3.x, sL[j]);
                    sH[j] = fmaf(v.x, w0.y, sH[j]); sH[j] = fmaf(v.y, w1.y, sH[j]);
                    sH[j] = fmaf(v.z, w2.y, sH[j]); sH[j] = fmaf(v.w, w3.y, sH[j]);
                }
            }
            const float2 bias = reinterpret_cast<const float2*>(h_bias)[q];
            float2* sl2 = reinterpret_cast<float2*>(g_sl);
#pragma unroll
            for (int j = 0; j < 8; ++j) {
                float2 v; v.x = sL[j] + bias.x; v.y = sH[j] + bias.y;
                sl2[(size_t)(nb + j) * 64 + q] = v;
            }
        } else {
            // ---- time-embed role: nodes c*64 .. c*64+63 ----
            const int c    = a - SL_BLOCKS;
            const int row  = tid >> 2;
            const int part = tid & 3;
            const int n    = c * 64 + row;
            if (n < N) {
                const float4* src = reinterpret_cast<const float4*>(
                    time_embed + (size_t)time_idx[n] * IN);
                float4* dst = reinterpret_cast<float4*>(
                    out + (size_t)N * OUT + (size_t)n * IN);
#pragma unroll
                for (int j = 0; j < 8; ++j)
                    dst[part * 8 + j] = src[part * 8 + j];
            }
        }
        return;
    }

    // ---- msg role: rel-sorted tile t ----
    const int t = bid - ((bid + 1) >> 3);
    if (t >= MSG_TILES) return;
    const int lo = t * 32;

    if (tid < 32) {
        int e = g_eid_r[lo + tid];
        ssrc[tid]  = edge_src[e];
        stype[tid] = edge_type[e];
        snorm[tid] = edge_norm[e];
        int d = edge_dst[e];
        int slot = atomicAdd(&g_cur_d[d], 1);
        if (slot > CAP - 1) slot = CAP - 1;   // unreachable for this input
        spos[tid] = d * CAP + slot;
    }
    __syncthreads();

    {   // gather 32 h-rows: 8 threads/row, 4 float4 each
        const int row = tid >> 3;
        const int c0  = (tid & 7) * 4;
        const float* hp = h + (size_t)ssrc[row] * IN;
        float* dst = &hsm[row * 132];
#pragma unroll
        for (int j = 0; j < 4; ++j) {
            float4 v = *reinterpret_cast<const float4*>(hp + c0 + 32 * j);
            *reinterpret_cast<float4*>(dst + c0 + 32 * j) = v;
        }
    }
    __syncthreads();

    const int slot = tid >> 7;           // 0,1
    const int o    = tid & 127;
    const int b    = o >> 4;
    const int ol   = o & 15;

#define MSG_BODY(K, W0, W1, W2, W3)                                          \
    {                                                                        \
        const float* hrow = &hsm[(K) * 132 + b * 16];                        \
        float4 h0 = *reinterpret_cast<const float4*>(hrow);                  \
        float4 h1 = *reinterpret_cast<const float4*>(hrow + 4);              \
        float4 h2 = *reinterpret_cast<const float4*>(hrow + 8);              \
        float4 h3 = *reinterpret_cast<const float4*>(hrow + 12);             \
        float m0 = 0.f, m1 = 0.f;                                            \
        m0 = fmaf(h0.x, W0.x, m0); m0 = fmaf(h0.y, W0.y, m0);                \
        m0 = fmaf(h0.z, W0.z, m0); m0 = fmaf(h0.w, W0.w, m0);                \
        m1 = fmaf(h1.x, W1.x, m1); m1 = fmaf(h1.y, W1.y, m1);                \
        m1 = fmaf(h1.z, W1.z, m1); m1 = fmaf(h1.w, W1.w, m1);                \
        m0 = fmaf(h2.x, W2.x, m0); m0 = fmaf(h2.y, W2.y, m0);                \
        m0 = fmaf(h2.z, W2.z, m0); m0 = fmaf(h2.w, W2.w, m0);                \
        m1 = fmaf(h3.x, W3.x, m1); m1 = fmaf(h3.y, W3.y, m1);                \
        m1 = fmaf(h3.z, W3.z, m1); m1 = fmaf(h3.w, W3.w, m1);                \
        __builtin_nontemporal_store(f2bf(snorm[K] * (m0 + m1)),              \
                                    &g_msg[(size_t)spos[K] * OUT + o]);      \
    }

    if (stype[0] == stype[31]) {
        const float4* wp = reinterpret_cast<const float4*>(
            g_W_t + (size_t)stype[0] * 2048 + b * 256 + ol * 16);
        float4 w0 = wp[0], w1 = wp[1], w2 = wp[2], w3 = wp[3];
#pragma unroll 4
        for (int k = slot; k < 32; k += 2)
            MSG_BODY(k, w0, w1, w2, w3)
    } else {
        int rcur = -1;
        float4 w0, w1, w2, w3;
        for (int k = slot; k < 32; k += 2) {
            int r = stype[k];
            if (r != rcur) {
                const float4* wp = reinterpret_cast<const float4*>(
                    g_W_t + (size_t)r * 2048 + b * 256 + ol * 16);
                w0 = wp[0]; w1 = wp[1]; w2 = wp[2]; w3 = wp[3];
                rcur = r;
            }
            MSG_BODY(k, w0, w1, w2, w3)
        }
    }
#undef MSG_BODY
}

// K4: segment-sum over claimed slots + nn scale + sl add + ReLU. 1250 blocks
// x 256 threads = 4 waves x 4 nodes each. No LDS, no GEMM. Tail re-zeroes
// g_cur_d / g_cnt_r / g_done for the next launch.
__global__ __launch_bounds__(256) void node_kernel(
        const float* __restrict__ node_norm,
        float* __restrict__ out) {
    const int t    = threadIdx.x;
    const int q    = t & 63;             // feature pair 2q, 2q+1
    const int wave = t >> 6;             // 0..3
    const int base = blockIdx.x * 16 + wave * 4;

    const unsigned* msg32 = reinterpret_cast<const unsigned*>(g_msg);
    const float2*   sl2   = reinterpret_cast<const float2*>(g_sl);
    float2*         o2    = reinterpret_cast<float2*>(out);

#pragma unroll
    for (int nl = 0; nl < 4; ++nl) {
        const int n  = base + nl;
        int cn = g_cur_d[n];
        if (cn > CAP) cn = CAP;
        const unsigned* mp = msg32 + (size_t)n * CAP * 64 + q;
        float aL0 = 0.f, aL1 = 0.f, aH0 = 0.f, aH1 = 0.f;
        int k = 0;
        for (; k + 3 < cn; k += 4) {
            unsigned m0 = __builtin_nontemporal_load(mp + (size_t)(k + 0) * 64);
            unsigned m1 = __builtin_nontemporal_load(mp + (size_t)(k + 1) * 64);
            unsigned m2 = __builtin_nontemporal_load(mp + (size_t)(k + 2) * 64);
            unsigned m3 = __builtin_nontemporal_load(mp + (size_t)(k + 3) * 64);
            aL0 += bflo(m0); aH0 += bfhi(m0);
            aL1 += bflo(m1); aH1 += bfhi(m1);
            aL0 += bflo(m2); aH0 += bfhi(m2);
            aL1 += bflo(m3); aH1 += bfhi(m3);
        }
        for (; k < cn; ++k) {
            unsigned m = __builtin_nontemporal_load(mp + (size_t)k * 64);
            aL0 += bflo(m); aH0 += bfhi(m);
        }
        const float nn = node_norm[n];
        const float2 sl = sl2[(size_t)n * 64 + q];
        float2 v;
        v.x = fmaxf((aL0 + aL1) * nn + sl.x, 0.f);
        v.y = fmaxf((aH0 + aH1) * nn + sl.y, 0.f);
        o2[(size_t)n * 64 + q] = v;
    }

    // ---- next-launch state zeroing (after all reads) ----
    __syncthreads();
    if (t < 16) g_cur_d[blockIdx.x * 16 + t] = 0;
    {
        int j = blockIdx.x * 256 + t;           // blocks 0..114 cover NSEG*16
        if (j < NSEG * 16) g_cnt_r[j] = 0;
    }
    if (blockIdx.x == 0 && t == 0) g_done = 0u;
}

extern "C" void kernel_launch(void* const* d_in, const int* in_sizes, int n_in,
                              void* d_out, int out_size, void* d_ws, size_t ws_size,
                              hipStream_t stream) {
    const float* h           = (const float*)d_in[0];
    const float* edge_norm   = (const float*)d_in[1];
    const float* node_norm   = (const float*)d_in[2];
    const float* weight      = (const float*)d_in[3];
    const float* h_bias      = (const float*)d_in[4];
    const float* loop_weight = (const float*)d_in[5];
    const float* time_embed  = (const float*)d_in[6];
    const int*   edge_src    = (const int*)d_in[7];
    const int*   edge_dst    = (const int*)d_in[8];
    const int*   edge_type   = (const int*)d_in[9];
    const int*   time_idx    = (const int*)d_in[10];
    float* out = (float*)d_out;

    build_kernel<<<400, 256, 0, stream>>>(weight, edge_type);
    scatter_kernel<<<(E + 255) / 256, 256, 0, stream>>>(edge_type);
    fused_kernel<<<GRID3, 256, 0, stream>>>(h, edge_norm, edge_src, edge_dst,
                                            edge_type, loop_weight, h_bias,
                                            time_embed, time_idx, out);
    node_kernel<<<N / 16, 256, 0, stream>>>(node_norm, out);
}

// Round 12
// 219.083 us; speedup vs baseline: 1.7084x; 1.7084x over previous
//
#include <hip/hip_runtime.h>

#define N 20000
#define E 200000
#define IN 128
#define OUT 128
#define NB 8
#define SI 16
#define SO 16
#define R 230
#define T 365

#define NSH 8                 // relation cursor shards (contention /8)
#define NSEG (R * NSH)        // 1840 (r,shard) segments

#define ALLOC_BLOCKS 86       // covers 20032 dst + 1856 rel slots
#define SL_BLOCKS 625         // self-loop role: 32 nodes/block
#define TE_BLOCKS 313         // time-embed role: 64 nodes/block
#define GRID2 (ALLOC_BLOCKS + SL_BLOCKS + TE_BLOCKS)   // 1024

// Scratch in module .bss (zero-initialized at load). d_ws untouched;
// kernel_launch does plain kernel launches only (graph-capture safe).
// Invariant: node_kernel's tail re-zeroes g_cnt_d / g_cnt_r / g_total_* for
// the NEXT launch; first launch rides .bss zero-init. g_cur_d / g_cur_r are
// rebuilt from counts by alloc each launch.
__device__ float  g_W_t[(size_t)R * NB * SO * SI]; // W transposed: [r][b][ol][i]
__device__ ushort g_msg[(size_t)E * OUT];          // messages (bf16), dst-packed
__device__ float  g_sl[(size_t)N * OUT];           // self-loop GEMM + bias
__device__ int    g_cnt_d[N];
__device__ int    g_off_d[N];
__device__ int    g_cur_d[N];                      // bumped by msg_kernel
__device__ int    g_cnt_r[NSEG * 16];              // line-padded shard counts
__device__ int    g_cur_r[NSEG * 16];
__device__ int    g_eid_r[E];                      // edge ids, (r,shard)-sorted
__device__ int    g_total_d;
__device__ int    g_total_r;

__device__ __forceinline__ ushort f2bf(float f) {  // RNE float->bf16
    unsigned u = __float_as_uint(f);
    return (ushort)((u + 0x7fffu + ((u >> 16) & 1u)) >> 16);
}
__device__ __forceinline__ float bflo(unsigned m) { return __uint_as_float(m << 16); }
__device__ __forceinline__ float bfhi(unsigned m) { return __uint_as_float(m & 0xffff0000u); }

// K1 (R9-verified): W transpose + dst histogram + sharded relation histogram.
__global__ __launch_bounds__(256) void hist_kernel(
        const float* __restrict__ weight,
        const int* __restrict__ edge_dst,
        const int* __restrict__ edge_type) {
    __shared__ int lh[NSEG];
    const int tid  = threadIdx.x;
    const int gtid = blockIdx.x * 256 + tid;
    const int GSZ  = gridDim.x * 256;

    for (int t = gtid; t < R * NB * SI * SO; t += GSZ) {
        int r  = t >> 11;
        int b  = (t >> 8) & 7;
        int ol = (t >> 4) & 15;
        int i  = t & 15;
        g_W_t[t] = weight[(size_t)r * 2048 + b * 256 + i * 16 + ol];
    }
    for (int j = tid; j < NSEG; j += 256) lh[j] = 0;
    __syncthreads();
    for (int e = gtid; e < E; e += GSZ) {
        atomicAdd(&g_cnt_d[edge_dst[e]], 1);
        atomicAdd(&lh[edge_type[e] * NSH + (e & (NSH - 1))], 1);
    }
    __syncthreads();
    for (int j = tid; j < NSEG; j += 256)
        if (lh[j]) atomicAdd(&g_cnt_r[j * 16], lh[j]);
}

// K2: wave-aggregated bump alloc (R9-verified, blocks 0..85) + independent
// aux roles riding the same launch slot: self-loop GEMM+bias -> g_sl
// (blocks 86..710, R11-verified code) and time-embed gather -> out2
// (blocks 711..1023, R11-verified code). Aux reads only pure inputs.
__global__ __launch_bounds__(256) void alloc_aux_kernel(
        const float* __restrict__ h,
        const float* __restrict__ loop_weight,
        const float* __restrict__ h_bias,
        const float* __restrict__ time_embed,
        const int* __restrict__ time_idx,
        float* __restrict__ out) {
    const int bid = blockIdx.x;
    const int tid = threadIdx.x;

    if (bid < ALLOC_BLOCKS) {
        const int idx  = bid * 256 + tid;
        const int lane = tid & 63;
        const int NPAD = 20032;                   // 313 waves
        if (idx < NPAD) {
            int c = (idx < N) ? g_cnt_d[idx] : 0;
            int x = c;
            for (int d = 1; d < 64; d <<= 1) {
                int y = __shfl_up(x, d);
                if (lane >= d) x += y;
            }
            int base = 0;
            if (lane == 63) base = atomicAdd(&g_total_d, x);
            base = __shfl(base, 63);
            if (idx < N) {
                int off = base + x - c;
                g_off_d[idx] = off;
                g_cur_d[idx] = off;
            }
        } else {
            int j = idx - NPAD;                    // [0, 1856) covers NSEG
            if (j < 1856) {
                int c = (j < NSEG) ? g_cnt_r[j * 16] : 0;
                int x = c;
                for (int d = 1; d < 64; d <<= 1) {
                    int y = __shfl_up(x, d);
                    if (lane >= d) x += y;
                }
                int base = 0;
                if (lane == 63) base = atomicAdd(&g_total_r, x);
                base = __shfl(base, 63);
                if (j < NSEG) g_cur_r[j * 16] = base + x - c;
            }
        }
        return;
    }

    if (bid < ALLOC_BLOCKS + SL_BLOCKS) {
        // ---- self-loop role: nodes a*32 .. a*32+31 ----
        const int a    = bid - ALLOC_BLOCKS;
        const int q    = tid & 63;                // feature pair 2q, 2q+1
        const int wave = tid >> 6;                // 0..3
        const int nb   = a * 32 + wave * 8;
        const float2* lw2 = reinterpret_cast<const float2*>(loop_weight);
        float sL[8], sH[8];
#pragma unroll
        for (int j = 0; j < 8; ++j) { sL[j] = 0.f; sH[j] = 0.f; }
        for (int i0 = 0; i0 < IN; i0 += 4) {
            float2 w0 = lw2[(size_t)(i0 + 0) * 64 + q];
            float2 w1 = lw2[(size_t)(i0 + 1) * 64 + q];
            float2 w2 = lw2[(size_t)(i0 + 2) * 64 + q];
            float2 w3 = lw2[(size_t)(i0 + 3) * 64 + q];
#pragma unroll
            for (int j = 0; j < 8; ++j) {
                float4 v = *reinterpret_cast<const float4*>(
                    h + (size_t)(nb + j) * IN + i0);   // wave-broadcast
                sL[j] = fmaf(v.x, w0.x, sL[j]); sL[j] = fmaf(v.y, w1.x, sL[j]);
                sL[j] = fmaf(v.z, w2.x, sL[j]); sL[j] = fmaf(v.w, w3.x, sL[j]);
                sH[j] = fmaf(v.x, w0.y, sH[j]); sH[j] = fmaf(v.y, w1.y, sH[j]);
                sH[j] = fmaf(v.z, w2.y, sH[j]); sH[j] = fmaf(v.w, w3.y, sH[j]);
            }
        }
        const float2 bias = reinterpret_cast<const float2*>(h_bias)[q];
        float2* sl2 = reinterpret_cast<float2*>(g_sl);
#pragma unroll
        for (int j = 0; j < 8; ++j) {
            float2 v; v.x = sL[j] + bias.x; v.y = sH[j] + bias.y;
            sl2[(size_t)(nb + j) * 64 + q] = v;
        }
        return;
    }

    // ---- time-embed role: nodes c*64 .. c*64+63 ----
    const int c    = bid - ALLOC_BLOCKS - SL_BLOCKS;   // 0..312
    const int row  = tid >> 2;
    const int part = tid & 3;
    const int n    = c * 64 + row;
    if (n < N) {
        const float4* src = reinterpret_cast<const float4*>(
            time_embed + (size_t)time_idx[n] * IN);
        float4* dst = reinterpret_cast<float4*>(
            out + (size_t)N * OUT + (size_t)n * IN);
#pragma unroll
        for (int j = 0; j < 8; ++j)
            dst[part * 8 + j] = src[part * 8 + j];
    }
}

// K3 (R9-verified): relation scatter with sharded cursors.
__global__ void scatter_kernel(const int* __restrict__ edge_type) {
    int e = blockIdx.x * blockDim.x + threadIdx.x;
    if (e < E) {
        int seg = edge_type[e] * NSH + (e & (NSH - 1));
        int pr = atomicAdd(&g_cur_r[seg * 16], 1);
        g_eid_r[pr] = e;
    }
}

// K4 (R9-verified): block-pipelined msg kernel, 32-edge rel-sorted tiles,
// W[r] in registers, dst slot claimed by one atomic in the meta phase,
// dense dst-packed bf16 NT stores.
__global__ __launch_bounds__(256) void msg_kernel(
        const float* __restrict__ h,
        const float* __restrict__ edge_norm,
        const int* __restrict__ edge_src,
        const int* __restrict__ edge_dst,
        const int* __restrict__ edge_type) {
    __shared__ __attribute__((aligned(16))) float hsm[32 * 132];
    __shared__ int   ssrc[32], stype[32], spos[32];
    __shared__ float snorm[32];

    const int tid = threadIdx.x;
    const int lo  = blockIdx.x * 32;

    if (tid < 32) {
        int e = g_eid_r[lo + tid];
        ssrc[tid]  = edge_src[e];
        stype[tid] = edge_type[e];
        snorm[tid] = edge_norm[e];
        spos[tid]  = atomicAdd(&g_cur_d[edge_dst[e]], 1);
    }
    __syncthreads();

    {   // gather 32 h-rows: 8 threads/row, 4 float4 each
        const int row = tid >> 3;
        const int c0  = (tid & 7) * 4;
        const float* hp = h + (size_t)ssrc[row] * IN;
        float* dst = &hsm[row * 132];
#pragma unroll
        for (int j = 0; j < 4; ++j) {
            float4 v = *reinterpret_cast<const float4*>(hp + c0 + 32 * j);
            *reinterpret_cast<float4*>(dst + c0 + 32 * j) = v;
        }
    }
    __syncthreads();

    const int slot = tid >> 7;           // 0,1
    const int o    = tid & 127;
    const int b    = o >> 4;
    const int ol   = o & 15;

#define MSG_BODY(K, W0, W1, W2, W3)                                          \
    {                                                                        \
        const float* hrow = &hsm[(K) * 132 + b * 16];                        \
        float4 h0 = *reinterpret_cast<const float4*>(hrow);                  \
        float4 h1 = *reinterpret_cast<const float4*>(hrow + 4);              \
        float4 h2 = *reinterpret_cast<const float4*>(hrow + 8);              \
        float4 h3 = *reinterpret_cast<const float4*>(hrow + 12);             \
        float m0 = 0.f, m1 = 0.f;                                            \
        m0 = fmaf(h0.x, W0.x, m0); m0 = fmaf(h0.y, W0.y, m0);                \
        m0 = fmaf(h0.z, W0.z, m0); m0 = fmaf(h0.w, W0.w, m0);                \
        m1 = fmaf(h1.x, W1.x, m1); m1 = fmaf(h1.y, W1.y, m1);                \
        m1 = fmaf(h1.z, W1.z, m1); m1 = fmaf(h1.w, W1.w, m1);                \
        m0 = fmaf(h2.x, W2.x, m0); m0 = fmaf(h2.y, W2.y, m0);                \
        m0 = fmaf(h2.z, W2.z, m0); m0 = fmaf(h2.w, W2.w, m0);                \
        m1 = fmaf(h3.x, W3.x, m1); m1 = fmaf(h3.y, W3.y, m1);                \
        m1 = fmaf(h3.z, W3.z, m1); m1 = fmaf(h3.w, W3.w, m1);                \
        __builtin_nontemporal_store(f2bf(snorm[K] * (m0 + m1)),              \
                                    &g_msg[(size_t)spos[K] * OUT + o]);      \
    }

    if (stype[0] == stype[31]) {
        const float4* wp = reinterpret_cast<const float4*>(
            g_W_t + (size_t)stype[0] * 2048 + b * 256 + ol * 16);
        float4 w0 = wp[0], w1 = wp[1], w2 = wp[2], w3 = wp[3];
#pragma unroll 4
        for (int k = slot; k < 32; k += 2)
            MSG_BODY(k, w0, w1, w2, w3)
    } else {
        int rcur = -1;
        float4 w0, w1, w2, w3;
        for (int k = slot; k < 32; k += 2) {
            int r = stype[k];
            if (r != rcur) {
                const float4* wp = reinterpret_cast<const float4*>(
                    g_W_t + (size_t)r * 2048 + b * 256 + ol * 16);
                w0 = wp[0]; w1 = wp[1]; w2 = wp[2]; w3 = wp[3];
                rcur = r;
            }
            MSG_BODY(k, w0, w1, w2, w3)
        }
    }
#undef MSG_BODY
}

// K5: segment-sum + nn scale + sl add + ReLU only (GEMM/bias/te moved to K2).
// 1250 blocks x 256 threads = 4 waves x 4 nodes each. Tail re-zeroes state.
__global__ __launch_bounds__(256) void node_kernel(
        const float* __restrict__ node_norm,
        float* __restrict__ out) {
    const int t    = threadIdx.x;
    const int q    = t & 63;             // feature pair 2q, 2q+1
    const int wave = t >> 6;             // 0..3
    const int base = blockIdx.x * 16 + wave * 4;

    const unsigned* msg32 = reinterpret_cast<const unsigned*>(g_msg);
    const float2*   sl2   = reinterpret_cast<const float2*>(g_sl);
    float2*         o2    = reinterpret_cast<float2*>(out);

#pragma unroll
    for (int nl = 0; nl < 4; ++nl) {
        const int n  = base + nl;
        const int st = g_off_d[n];
        const int cn = g_cnt_d[n];
        const unsigned* mp = msg32 + (size_t)st * 64 + q;
        float aL0 = 0.f, aL1 = 0.f, aH0 = 0.f, aH1 = 0.f;
        int k = 0;
        for (; k + 3 < cn; k += 4) {
            unsigned m0 = __builtin_nontemporal_load(mp + (size_t)(k + 0) * 64);
            unsigned m1 = __builtin_nontemporal_load(mp + (size_t)(k + 1) * 64);
            unsigned m2 = __builtin_nontemporal_load(mp + (size_t)(k + 2) * 64);
            unsigned m3 = __builtin_nontemporal_load(mp + (size_t)(k + 3) * 64);
            aL0 += bflo(m0); aH0 += bfhi(m0);
            aL1 += bflo(m1); aH1 += bfhi(m1);
            aL0 += bflo(m2); aH0 += bfhi(m2);
            aL1 += bflo(m3); aH1 += bfhi(m3);
        }
        for (; k < cn; ++k) {
            unsigned m = __builtin_nontemporal_load(mp + (size_t)k * 64);
            aL0 += bflo(m); aH0 += bfhi(m);
        }
        const float nn = node_norm[n];
        const float2 sl = sl2[(size_t)n * 64 + q];
        float2 v;
        v.x = fmaxf((aL0 + aL1) * nn + sl.x, 0.f);
        v.y = fmaxf((aH0 + aH1) * nn + sl.y, 0.f);
        o2[(size_t)n * 64 + q] = v;
    }

    // ---- next-launch state zeroing (after all reads) ----
    __syncthreads();
    if (t < 16) g_cnt_d[blockIdx.x * 16 + t] = 0;
    {
        int j = blockIdx.x * 256 + t;           // blocks 0..114 cover NSEG*16
        if (j < NSEG * 16) g_cnt_r[j] = 0;
    }
    if (blockIdx.x == 0 && t == 0) { g_total_d = 0; g_total_r = 0; }
}

extern "C" void kernel_launch(void* const* d_in, const int* in_sizes, int n_in,
                              void* d_out, int out_size, void* d_ws, size_t ws_size,
                              hipStream_t stream) {
    const float* h           = (const float*)d_in[0];
    const float* edge_norm   = (const float*)d_in[1];
    const float* node_norm   = (const float*)d_in[2];
    const float* weight      = (const float*)d_in[3];
    const float* h_bias      = (const float*)d_in[4];
    const float* loop_weight = (const float*)d_in[5];
    const float* time_embed  = (const float*)d_in[6];
    const int*   edge_src    = (const int*)d_in[7];
    const int*   edge_dst    = (const int*)d_in[8];
    const int*   edge_type   = (const int*)d_in[9];
    const int*   time_idx    = (const int*)d_in[10];
    float* out = (float*)d_out;

    hist_kernel<<<400, 256, 0, stream>>>(weight, edge_dst, edge_type);
    alloc_aux_kernel<<<GRID2, 256, 0, stream>>>(h, loop_weight, h_bias,
                                                time_embed, time_idx, out);
    scatter_kernel<<<(E + 255) / 256, 256, 0, stream>>>(edge_type);
    msg_kernel<<<E / 32, 256, 0, stream>>>(h, edge_norm, edge_src,
                                           edge_dst, edge_type);
    node_kernel<<<N / 16, 256, 0, stream>>>(node_norm, out);
}

// Round 13
// 199.422 us; speedup vs baseline: 1.8768x; 1.0986x over previous
//
#include <hip/hip_runtime.h>

#define N 20000
#define E 200000
#define IN 128
#define OUT 128
#define NB 8
#define SI 16
#define SO 16
#define R 230
#define T 365

#define NSH 8                 // relation cursor shards (contention /8)
#define NSEG (R * NSH)        // 1840 (r,shard) segments

#define ALLOC_BLOCKS 86       // covers 20032 dst + 1856 rel slots
#define SL_BLOCKS 625         // self-loop role: 32 nodes/block
#define TE_BLOCKS 313         // time-embed role: 64 nodes/block
#define GRID2 (ALLOC_BLOCKS + SL_BLOCKS + TE_BLOCKS)   // 1024

// Scratch in module .bss (zero-initialized at load). d_ws untouched;
// kernel_launch does plain kernel launches only (graph-capture safe).
// Invariant: node_kernel's tail re-zeroes g_cnt_d / g_cnt_r / g_total_* for
// the NEXT launch; first launch rides .bss zero-init. g_cur_d / g_cur_r are
// rebuilt from counts by alloc each launch.
__device__ float  g_W_t[(size_t)R * NB * SO * SI]; // W transposed: [r][b][ol][i]
__device__ ushort g_msg[(size_t)E * OUT];          // messages (bf16), dst-packed
__device__ float  g_sl[(size_t)N * OUT];           // self-loop GEMM + bias
__device__ int    g_cnt_d[N];
__device__ int    g_off_d[N];
__device__ int    g_cur_d[N];                      // bumped by msg_kernel
__device__ int    g_cnt_r[NSEG * 16];              // line-padded shard counts
__device__ int    g_cur_r[NSEG * 16];
__device__ int    g_eid_r[E];                      // edge ids, (r,shard)-sorted
__device__ int    g_total_d;
__device__ int    g_total_r;

__device__ __forceinline__ ushort f2bf(float f) {  // RNE float->bf16
    unsigned u = __float_as_uint(f);
    return (ushort)((u + 0x7fffu + ((u >> 16) & 1u)) >> 16);
}
__device__ __forceinline__ float bflo(unsigned m) { return __uint_as_float(m << 16); }
__device__ __forceinline__ float bfhi(unsigned m) { return __uint_as_float(m & 0xffff0000u); }

// K1 (R9-verified): W transpose + dst histogram + sharded relation histogram.
__global__ __launch_bounds__(256) void hist_kernel(
        const float* __restrict__ weight,
        const int* __restrict__ edge_dst,
        const int* __restrict__ edge_type) {
    __shared__ int lh[NSEG];
    const int tid  = threadIdx.x;
    const int gtid = blockIdx.x * 256 + tid;
    const int GSZ  = gridDim.x * 256;

    for (int t = gtid; t < R * NB * SI * SO; t += GSZ) {
        int r  = t >> 11;
        int b  = (t >> 8) & 7;
        int ol = (t >> 4) & 15;
        int i  = t & 15;
        g_W_t[t] = weight[(size_t)r * 2048 + b * 256 + i * 16 + ol];
    }
    for (int j = tid; j < NSEG; j += 256) lh[j] = 0;
    __syncthreads();
    for (int e = gtid; e < E; e += GSZ) {
        atomicAdd(&g_cnt_d[edge_dst[e]], 1);
        atomicAdd(&lh[edge_type[e] * NSH + (e & (NSH - 1))], 1);
    }
    __syncthreads();
    for (int j = tid; j < NSEG; j += 256)
        if (lh[j]) atomicAdd(&g_cnt_r[j * 16], lh[j]);
}

// K2: wave-aggregated bump alloc (blocks 0..85) + aux roles in the same
// launch slot: self-loop GEMM+bias -> g_sl (blocks 86..710; h tile staged in
// LDS coalesced — R12's wave-broadcast GLOBAL reads were the 50 us bug) and
// time-embed gather -> out2 (blocks 711..1023). Aux reads only pure inputs.
__global__ __launch_bounds__(256) void alloc_aux_kernel(
        const float* __restrict__ h,
        const float* __restrict__ loop_weight,
        const float* __restrict__ h_bias,
        const float* __restrict__ time_embed,
        const int* __restrict__ time_idx,
        float* __restrict__ out) {
    __shared__ __attribute__((aligned(16))) float hsm[32 * 132];  // sl role
    const int bid = blockIdx.x;
    const int tid = threadIdx.x;

    if (bid < ALLOC_BLOCKS) {
        const int idx  = bid * 256 + tid;
        const int lane = tid & 63;
        const int NPAD = 20032;                   // 313 waves
        if (idx < NPAD) {
            int c = (idx < N) ? g_cnt_d[idx] : 0;
            int x = c;
            for (int d = 1; d < 64; d <<= 1) {
                int y = __shfl_up(x, d);
                if (lane >= d) x += y;
            }
            int base = 0;
            if (lane == 63) base = atomicAdd(&g_total_d, x);
            base = __shfl(base, 63);
            if (idx < N) {
                int off = base + x - c;
                g_off_d[idx] = off;
                g_cur_d[idx] = off;
            }
        } else {
            int j = idx - NPAD;                    // [0, 1856) covers NSEG
            if (j < 1856) {
                int c = (j < NSEG) ? g_cnt_r[j * 16] : 0;
                int x = c;
                for (int d = 1; d < 64; d <<= 1) {
                    int y = __shfl_up(x, d);
                    if (lane >= d) x += y;
                }
                int base = 0;
                if (lane == 63) base = atomicAdd(&g_total_r, x);
                base = __shfl(base, 63);
                if (j < NSEG) g_cur_r[j * 16] = base + x - c;
            }
        }
        return;
    }

    if (bid < ALLOC_BLOCKS + SL_BLOCKS) {
        // ---- self-loop role: nodes a*32 .. a*32+31, h tile in LDS ----
        const int a   = bid - ALLOC_BLOCKS;
        const int nb0 = a * 32;

        for (int k = tid; k < 32 * IN; k += 256) {   // coalesced stage
            int nl = k >> 7;
            int i  = k & 127;
            hsm[nl * 132 + i] = h[(size_t)(nb0 + nl) * IN + i];
        }
        __syncthreads();

        const int q    = tid & 63;                // feature pair 2q, 2q+1
        const int wave = tid >> 6;                // 0..3
        const int nb   = wave * 8;                // local node base
        const float2* lw2 = reinterpret_cast<const float2*>(loop_weight);
        float sL[8], sH[8];
#pragma unroll
        for (int j = 0; j < 8; ++j) { sL[j] = 0.f; sH[j] = 0.f; }
        for (int i0 = 0; i0 < IN; i0 += 4) {
            float2 w0 = lw2[(size_t)(i0 + 0) * 64 + q];
            float2 w1 = lw2[(size_t)(i0 + 1) * 64 + q];
            float2 w2 = lw2[(size_t)(i0 + 2) * 64 + q];
            float2 w3 = lw2[(size_t)(i0 + 3) * 64 + q];
#pragma unroll
            for (int j = 0; j < 8; ++j) {
                float4 v = *reinterpret_cast<const float4*>(
                    &hsm[(nb + j) * 132 + i0]);       // LDS broadcast (free)
                sL[j] = fmaf(v.x, w0.x, sL[j]); sL[j] = fmaf(v.y, w1.x, sL[j]);
                sL[j] = fmaf(v.z, w2.x, sL[j]); sL[j] = fmaf(v.w, w3.x, sL[j]);
                sH[j] = fmaf(v.x, w0.y, sH[j]); sH[j] = fmaf(v.y, w1.y, sH[j]);
                sH[j] = fmaf(v.z, w2.y, sH[j]); sH[j] = fmaf(v.w, w3.y, sH[j]);
            }
        }
        const float2 bias = reinterpret_cast<const float2*>(h_bias)[q];
        float2* sl2 = reinterpret_cast<float2*>(g_sl);
#pragma unroll
        for (int j = 0; j < 8; ++j) {
            float2 v; v.x = sL[j] + bias.x; v.y = sH[j] + bias.y;
            sl2[(size_t)(nb0 + nb + j) * 64 + q] = v;
        }
        return;
    }

    // ---- time-embed role: nodes c*64 .. c*64+63 ----
    const int c    = bid - ALLOC_BLOCKS - SL_BLOCKS;   // 0..312
    const int row  = tid >> 2;
    const int part = tid & 3;
    const int n    = c * 64 + row;
    if (n < N) {
        const float4* src = reinterpret_cast<const float4*>(
            time_embed + (size_t)time_idx[n] * IN);
        float4* dst = reinterpret_cast<float4*>(
            out + (size_t)N * OUT + (size_t)n * IN);
#pragma unroll
        for (int j = 0; j < 8; ++j)
            dst[part * 8 + j] = src[part * 8 + j];
    }
}

// K3 (R9-verified): relation scatter with sharded cursors.
__global__ void scatter_kernel(const int* __restrict__ edge_type) {
    int e = blockIdx.x * blockDim.x + threadIdx.x;
    if (e < E) {
        int seg = edge_type[e] * NSH + (e & (NSH - 1));
        int pr = atomicAdd(&g_cur_r[seg * 16], 1);
        g_eid_r[pr] = e;
    }
}

// K4 (R9-verified): block-pipelined msg kernel, 32-edge rel-sorted tiles,
// W[r] in registers, dst slot claimed by one atomic in the meta phase,
// dense dst-packed bf16 NT stores.
__global__ __launch_bounds__(256) void msg_kernel(
        const float* __restrict__ h,
        const float* __restrict__ edge_norm,
        const int* __restrict__ edge_src,
        const int* __restrict__ edge_dst,
        const int* __restrict__ edge_type) {
    __shared__ __attribute__((aligned(16))) float hsm[32 * 132];
    __shared__ int   ssrc[32], stype[32], spos[32];
    __shared__ float snorm[32];

    const int tid = threadIdx.x;
    const int lo  = blockIdx.x * 32;

    if (tid < 32) {
        int e = g_eid_r[lo + tid];
        ssrc[tid]  = edge_src[e];
        stype[tid] = edge_type[e];
        snorm[tid] = edge_norm[e];
        spos[tid]  = atomicAdd(&g_cur_d[edge_dst[e]], 1);
    }
    __syncthreads();

    {   // gather 32 h-rows: 8 threads/row, 4 float4 each
        const int row = tid >> 3;
        const int c0  = (tid & 7) * 4;
        const float* hp = h + (size_t)ssrc[row] * IN;
        float* dst = &hsm[row * 132];
#pragma unroll
        for (int j = 0; j < 4; ++j) {
            float4 v = *reinterpret_cast<const float4*>(hp + c0 + 32 * j);
            *reinterpret_cast<float4*>(dst + c0 + 32 * j) = v;
        }
    }
    __syncthreads();

    const int slot = tid >> 7;           // 0,1
    const int o    = tid & 127;
    const int b    = o >> 4;
    const int ol   = o & 15;

#define MSG_BODY(K, W0, W1, W2, W3)                                          \
    {                                                                        \
        const float* hrow = &hsm[(K) * 132 + b * 16];                        \
        float4 h0 = *reinterpret_cast<const float4*>(hrow);                  \
        float4 h1 = *reinterpret_cast<const float4*>(hrow + 4);              \
        float4 h2 = *reinterpret_cast<const float4*>(hrow + 8);              \
        float4 h3 = *reinterpret_cast<const float4*>(hrow + 12);             \
        float m0 = 0.f, m1 = 0.f;                                            \
        m0 = fmaf(h0.x, W0.x, m0); m0 = fmaf(h0.y, W0.y, m0);                \
        m0 = fmaf(h0.z, W0.z, m0); m0 = fmaf(h0.w, W0.w, m0);                \
        m1 = fmaf(h1.x, W1.x, m1); m1 = fmaf(h1.y, W1.y, m1);                \
        m1 = fmaf(h1.z, W1.z, m1); m1 = fmaf(h1.w, W1.w, m1);                \
        m0 = fmaf(h2.x, W2.x, m0); m0 = fmaf(h2.y, W2.y, m0);                \
        m0 = fmaf(h2.z, W2.z, m0); m0 = fmaf(h2.w, W2.w, m0);                \
        m1 = fmaf(h3.x, W3.x, m1); m1 = fmaf(h3.y, W3.y, m1);                \
        m1 = fmaf(h3.z, W3.z, m1); m1 = fmaf(h3.w, W3.w, m1);                \
        __builtin_nontemporal_store(f2bf(snorm[K] * (m0 + m1)),              \
                                    &g_msg[(size_t)spos[K] * OUT + o]);      \
    }

    if (stype[0] == stype[31]) {
        const float4* wp = reinterpret_cast<const float4*>(
            g_W_t + (size_t)stype[0] * 2048 + b * 256 + ol * 16);
        float4 w0 = wp[0], w1 = wp[1], w2 = wp[2], w3 = wp[3];
#pragma unroll 4
        for (int k = slot; k < 32; k += 2)
            MSG_BODY(k, w0, w1, w2, w3)
    } else {
        int rcur = -1;
        float4 w0, w1, w2, w3;
        for (int k = slot; k < 32; k += 2) {
            int r = stype[k];
            if (r != rcur) {
                const float4* wp = reinterpret_cast<const float4*>(
                    g_W_t + (size_t)r * 2048 + b * 256 + ol * 16);
                w0 = wp[0]; w1 = wp[1]; w2 = wp[2]; w3 = wp[3];
                rcur = r;
            }
            MSG_BODY(k, w0, w1, w2, w3)
        }
    }
#undef MSG_BODY
}

// K5 (R12-verified): segment-sum + nn scale + sl add + ReLU. 1250 blocks x
// 256 threads = 4 waves x 4 nodes each. Tail re-zeroes state.
__global__ __launch_bounds__(256) void node_kernel(
        const float* __restrict__ node_norm,
        float* __restrict__ out) {
    const int t    = threadIdx.x;
    const int q    = t & 63;             // feature pair 2q, 2q+1
    const int wave = t >> 6;             // 0..3
    const int base = blockIdx.x * 16 + wave * 4;

    const unsigned* msg32 = reinterpret_cast<const unsigned*>(g_msg);
    const float2*   sl2   = reinterpret_cast<const float2*>(g_sl);
    float2*         o2    = reinterpret_cast<float2*>(out);

#pragma unroll
    for (int nl = 0; nl < 4; ++nl) {
        const int n  = base + nl;
        const int st = g_off_d[n];
        const int cn = g_cnt_d[n];
        const unsigned* mp = msg32 + (size_t)st * 64 + q;
        float aL0 = 0.f, aL1 = 0.f, aH0 = 0.f, aH1 = 0.f;
        int k = 0;
        for (; k + 3 < cn; k += 4) {
            unsigned m0 = __builtin_nontemporal_load(mp + (size_t)(k + 0) * 64);
            unsigned m1 = __builtin_nontemporal_load(mp + (size_t)(k + 1) * 64);
            unsigned m2 = __builtin_nontemporal_load(mp + (size_t)(k + 2) * 64);
            unsigned m3 = __builtin_nontemporal_load(mp + (size_t)(k + 3) * 64);
            aL0 += bflo(m0); aH0 += bfhi(m0);
            aL1 += bflo(m1); aH1 += bfhi(m1);
            aL0 += bflo(m2); aH0 += bfhi(m2);
            aL1 += bflo(m3); aH1 += bfhi(m3);
        }
        for (; k < cn; ++k) {
            unsigned m = __builtin_nontemporal_load(mp + (size_t)k * 64);
            aL0 += bflo(m); aH0 += bfhi(m);
        }
        const float nn = node_norm[n];
        const float2 sl = sl2[(size_t)n * 64 + q];
        float2 v;
        v.x = fmaxf((aL0 + aL1) * nn + sl.x, 0.f);
        v.y = fmaxf((aH0 + aH1) * nn + sl.y, 0.f);
        o2[(size_t)n * 64 + q] = v;
    }

    // ---- next-launch state zeroing (after all reads) ----
    __syncthreads();
    if (t < 16) g_cnt_d[blockIdx.x * 16 + t] = 0;
    {
        int j = blockIdx.x * 256 + t;           // blocks 0..114 cover NSEG*16
        if (j < NSEG * 16) g_cnt_r[j] = 0;
    }
    if (blockIdx.x == 0 && t == 0) { g_total_d = 0; g_total_r = 0; }
}

extern "C" void kernel_launch(void* const* d_in, const int* in_sizes, int n_in,
                              void* d_out, int out_size, void* d_ws, size_t ws_size,
                              hipStream_t stream) {
    const float* h           = (const float*)d_in[0];
    const float* edge_norm   = (const float*)d_in[1];
    const float* node_norm   = (const float*)d_in[2];
    const float* weight      = (const float*)d_in[3];
    const float* h_bias      = (const float*)d_in[4];
    const float* loop_weight = (const float*)d_in[5];
    const float* time_embed  = (const float*)d_in[6];
    const int*   edge_src    = (const int*)d_in[7];
    const int*   edge_dst    = (const int*)d_in[8];
    const int*   edge_type   = (const int*)d_in[9];
    const int*   time_idx    = (const int*)d_in[10];
    float* out = (float*)d_out;

    hist_kernel<<<400, 256, 0, stream>>>(weight, edge_dst, edge_type);
    alloc_aux_kernel<<<GRID2, 256, 0, stream>>>(h, loop_weight, h_bias,
                                                time_embed, time_idx, out);
    scatter_kernel<<<(E + 255) / 256, 256, 0, stream>>>(edge_type);
    msg_kernel<<<E / 32, 256, 0, stream>>>(h, edge_norm, edge_src,
                                           edge_dst, edge_type);
    node_kernel<<<N / 16, 256, 0, stream>>>(node_norm, out);
}